// Round 6
// baseline (288.947 us; speedup 1.0000x reference)
//
#include <hip/hip_runtime.h>
#include <hip/hip_bf16.h>
#include <math.h>

#define B 2
#define S 2048
#define D 1024
#define H 16
#define HD 64
#define SCALE 0.125f
#define NEGBIG -1e30f
#define TQ 64

typedef _Float16 f16;
typedef _Float16 f16x8 __attribute__((ext_vector_type(8)));
typedef _Float16 f16x4 __attribute__((ext_vector_type(4)));
typedef float f32x4  __attribute__((ext_vector_type(4)));

__device__ __forceinline__ void gl_lds16(const void* g, void* l) {
    __builtin_amdgcn_global_load_lds(
        (const __attribute__((address_space(1))) unsigned int*)g,
        (__attribute__((address_space(3))) unsigned int*)l, 16, 0, 0);
}

// ---------------- fp32 -> (hi, lo) fp16 split (8 elem/thread) ----------------
__global__ __launch_bounds__(256) void split2_k(const float4* __restrict__ src,
                                                f16x8* __restrict__ hi,
                                                f16x8* __restrict__ lo, int n8) {
    int i = blockIdx.x * blockDim.x + threadIdx.x;
    if (i >= n8) return;
    float4 a = src[2 * i], b = src[2 * i + 1];
    float v[8] = {a.x, a.y, a.z, a.w, b.x, b.y, b.z, b.w};
    f16x8 h, l;
    #pragma unroll
    for (int j = 0; j < 8; j++) {
        f16 hh = (f16)v[j];
        h[j] = hh;
        l[j] = (f16)(v[j] - (float)hh);
    }
    hi[i] = h; lo[i] = l;
}

// ---------------- all 4 weight matrices -> fp16 in one launch ----------------
// wq/wk/wv concat into wqkv rows [0:1024/1024:2048/2048:3072]; wo separate.
__global__ __launch_bounds__(256) void convw_k(
    const float4* __restrict__ wq, const float4* __restrict__ wk,
    const float4* __restrict__ wv, const float4* __restrict__ wo,
    f16x8* __restrict__ wqkv, f16x8* __restrict__ woh, int n8) {
    int i = blockIdx.x * blockDim.x + threadIdx.x;
    if (i >= 4 * n8) return;
    int id = i / n8;
    int j = i - id * n8;
    const float4* src = (id == 0) ? wq : (id == 1) ? wk : (id == 2) ? wv : wo;
    f16x8* dst = (id < 3) ? (wqkv + (size_t)id * n8 + j) : (woh + j);
    float4 a = src[2 * j], b = src[2 * j + 1];
    f16x8 h;
    h[0] = (f16)a.x; h[1] = (f16)a.y; h[2] = (f16)a.z; h[3] = (f16)a.w;
    h[4] = (f16)b.x; h[5] = (f16)b.y; h[6] = (f16)b.z; h[7] = (f16)b.w;
    *dst = h;
}

// ---------------- document span bounds (ids are sorted) ----------------
__global__ void docbounds_k(const int* __restrict__ doc, int* __restrict__ dstart,
                            int* __restrict__ dend) {
    int i = blockIdx.x * blockDim.x + threadIdx.x;
    if (i >= S) return;
    int v = doc[i];
    int lo = 0, hi = S;
    while (lo < hi) { int mid = (lo + hi) >> 1; if (doc[mid] < v) lo = mid + 1; else hi = mid; }
    dstart[i] = lo;
    lo = 0; hi = S;
    while (lo < hi) { int mid = (lo + hi) >> 1; if (doc[mid] <= v) lo = mid + 1; else hi = mid; }
    dend[i] = lo;
}

// ================= fused QKV projection: 128x256 tile, merged N=3072 =========
// A (X) exact hi+lo fp16, B (wqkv) fp16. 4 waves 2x2, wave-tile 64m x 128n.
__global__ __launch_bounds__(256) void qkv_mfma_k(
    const f16* __restrict__ xh, const f16* __restrict__ xl,
    const f16* __restrict__ wqkv,
    const float* __restrict__ bq, const float* __restrict__ bk,
    const float* __restrict__ bv,
    f16* __restrict__ Qh, f16* __restrict__ Ql,
    f16* __restrict__ Kh, f16* __restrict__ Vth)
{
    __shared__ union {
        struct { f16 Ah[128 * 32]; f16 Al[128 * 32]; f16 Bh[256 * 32]; } s;
        f16 tr[128 * 136];     // V transpose, pad 8
    } lds;

    const int tid = threadIdx.x;
    const int w = tid >> 6, ln = tid & 63;
    const int wm = (w & 1) * 64, wn = (w >> 1) * 128;
    const int lc = ln & 15, quad = ln >> 4;
    const int srow = ln >> 2, slot = ln & 3;
    const int m0 = blockIdx.y * 128, n0 = blockIdx.x * 256;

    int a_off[4], b_off[8];
    #pragma unroll
    for (int t = 0; t < 4; t++) {
        int am = wm + t * 16 + lc;
        a_off[t] = am * 32 + ((quad ^ ((am >> 1) & 3)) * 8);
    }
    #pragma unroll
    for (int t = 0; t < 8; t++) {
        int bn = wn + t * 16 + lc;
        b_off[t] = bn * 32 + ((quad ^ ((bn >> 1) & 3)) * 8);
    }

    f32x4 acc[4][8];
    #pragma unroll
    for (int i = 0; i < 4; i++)
        #pragma unroll
        for (int j = 0; j < 8; j++) acc[i][j] = (f32x4){0.f, 0.f, 0.f, 0.f};

    for (int k0 = 0; k0 < 1024; k0 += 32) {
        #pragma unroll
        for (int half = 0; half < 2; half++) {
            int rl = half * 64 + w * 16 + srow;
            int q = slot ^ ((rl >> 1) & 3);
            size_t ga = (size_t)(m0 + rl) * 1024 + k0 + q * 8;
            int lofs = (half * 64 + w * 16) * 32;
            gl_lds16(xh + ga, lds.s.Ah + lofs);
            gl_lds16(xl + ga, lds.s.Al + lofs);
        }
        #pragma unroll
        for (int qr = 0; qr < 4; qr++) {
            int rl = qr * 64 + w * 16 + srow;
            int q = slot ^ ((rl >> 1) & 3);
            size_t gb = (size_t)(n0 + rl) * 1024 + k0 + q * 8;
            int lofs = (qr * 64 + w * 16) * 32;
            gl_lds16(wqkv + gb, lds.s.Bh + lofs);
        }
        __syncthreads();

        f16x8 ah[4], al[4], bh[8];
        #pragma unroll
        for (int t = 0; t < 4; t++) {
            ah[t] = *(const f16x8*)&lds.s.Ah[a_off[t]];
            al[t] = *(const f16x8*)&lds.s.Al[a_off[t]];
        }
        #pragma unroll
        for (int t = 0; t < 8; t++) bh[t] = *(const f16x8*)&lds.s.Bh[b_off[t]];

        #pragma unroll
        for (int mt = 0; mt < 4; mt++)
            #pragma unroll
            for (int nt = 0; nt < 8; nt++) {
                acc[mt][nt] = __builtin_amdgcn_mfma_f32_16x16x32_f16(al[mt], bh[nt], acc[mt][nt], 0, 0, 0);
                acc[mt][nt] = __builtin_amdgcn_mfma_f32_16x16x32_f16(ah[mt], bh[nt], acc[mt][nt], 0, 0, 0);
            }
        __syncthreads();
    }

    const int which = n0 >> 10;            // 0=Q 1=K 2=V
    const int ncol = n0 & 1023;
    const int bb = m0 >> 11;

    if (which < 2) {
        const float* bias = (which == 0) ? bq : bk;
        #pragma unroll
        for (int nt = 0; nt < 8; nt++) {
            int col = ncol + wn + nt * 16 + lc;
            float bv_ = bias[col];
            int h = col >> 6, hd = col & 63;
            #pragma unroll
            for (int mt = 0; mt < 4; mt++) {
                #pragma unroll
                for (int r = 0; r < 4; r++) {
                    int m = m0 + wm + mt * 16 + quad * 4 + r;
                    int s = m & (S - 1);
                    int bbm = m >> 11;
                    float val = acc[mt][nt][r] + bv_;
                    size_t idx = (((size_t)(bbm * H + h) * S) + s) * HD + hd;
                    if (which == 0) {
                        val *= SCALE;
                        f16 hh = (f16)val;
                        Qh[idx] = hh;
                        Ql[idx] = (f16)(val - (float)hh);
                    } else {
                        Kh[idx] = (f16)val;
                    }
                }
            }
        }
    } else {
        // V: two-pass LDS transpose, coalesced f16x8 stores along s
        const int sbase = m0 & (S - 1);
        #pragma unroll
        for (int pass = 0; pass < 2; pass++) {
            if ((w >> 1) == pass) {
                #pragma unroll
                for (int nt = 0; nt < 8; nt++) {
                    int colp = nt * 16 + lc;                 // 0..127 in-pass
                    int vcol = ncol + pass * 128 + colp;
                    float bv_ = bv[vcol];
                    #pragma unroll
                    for (int mt = 0; mt < 4; mt++) {
                        f16x4 v;
                        #pragma unroll
                        for (int r = 0; r < 4; r++) v[r] = (f16)(acc[mt][nt][r] + bv_);
                        *(f16x4*)&lds.tr[colp * 136 + wm + mt * 16 + quad * 4] = v;
                    }
                }
            }
            __syncthreads();
            #pragma unroll
            for (int p2 = 0; p2 < 8; p2++) {
                int chunk = tid + p2 * 256;     // 0..2047
                int colp = chunk >> 4;          // 0..127
                int oct = chunk & 15;
                f16x8 v = *(const f16x8*)&lds.tr[colp * 136 + oct * 8];
                int vcol = ncol + pass * 128 + colp;
                int h = vcol >> 6, hd = vcol & 63;
                size_t idx = (((size_t)(bb * H + h) * HD) + hd) * S + sbase + oct * 8;
                *(f16x8*)(Vth + idx) = v;
            }
            __syncthreads();
        }
    }
}

// ---------------- output projection (MFMA, 128x128) ----------------
__device__ __forceinline__ void gemm_core128(
    const f16* __restrict__ Ahg, const f16* __restrict__ Alg,
    const f16* __restrict__ Bhg,
    int m0, int n0, f16* Ah, f16* Al, f16* Bh, f32x4 acc[4][4])
{
    const int tid = threadIdx.x;
    const int w = tid >> 6;
    const int ln = tid & 63;
    const int wm = (w & 1) * 64, wn = (w >> 1) * 64;
    const int lc = ln & 15;
    const int quad = ln >> 4;
    const int srow = ln >> 2;
    const int slot = ln & 3;

    int a_off[4], b_off[4];
    #pragma unroll
    for (int t = 0; t < 4; t++) {
        int am = wm + t * 16 + lc;
        a_off[t] = am * 32 + ((quad ^ ((am >> 1) & 3)) * 8);
        int bn = wn + t * 16 + lc;
        b_off[t] = bn * 32 + ((quad ^ ((bn >> 1) & 3)) * 8);
    }

    for (int k0 = 0; k0 < 1024; k0 += 32) {
        #pragma unroll
        for (int half = 0; half < 2; half++) {
            int rl = half * 64 + w * 16 + srow;
            int q = slot ^ ((rl >> 1) & 3);
            size_t ga = (size_t)(m0 + rl) * 1024 + k0 + q * 8;
            size_t gb = (size_t)(n0 + rl) * 1024 + k0 + q * 8;
            int lofs = (half * 64 + w * 16) * 32;
            gl_lds16(Ahg + ga, Ah + lofs);
            gl_lds16(Alg + ga, Al + lofs);
            gl_lds16(Bhg + gb, Bh + lofs);
        }
        __syncthreads();

        f16x8 ah[4], al[4], bh[4];
        #pragma unroll
        for (int t = 0; t < 4; t++) {
            ah[t] = *(const f16x8*)&Ah[a_off[t]];
            al[t] = *(const f16x8*)&Al[a_off[t]];
            bh[t] = *(const f16x8*)&Bh[b_off[t]];
        }
        #pragma unroll
        for (int mt = 0; mt < 4; mt++)
            #pragma unroll
            for (int nt = 0; nt < 4; nt++) {
                acc[mt][nt] = __builtin_amdgcn_mfma_f32_16x16x32_f16(al[mt], bh[nt], acc[mt][nt], 0, 0, 0);
                acc[mt][nt] = __builtin_amdgcn_mfma_f32_16x16x32_f16(ah[mt], bh[nt], acc[mt][nt], 0, 0, 0);
            }
        __syncthreads();
    }
}

__global__ __launch_bounds__(256) void out_mfma_k(
    const f16* __restrict__ oh, const f16* __restrict__ ol,
    const f16* __restrict__ wh,
    const float* __restrict__ bias, float* __restrict__ Y)
{
    __shared__ f16 Ah[128 * 32], Al[128 * 32], Bh[128 * 32];
    const int m0 = blockIdx.y * 128, n0 = blockIdx.x * 128;
    f32x4 acc[4][4];
    #pragma unroll
    for (int i = 0; i < 4; i++)
        #pragma unroll
        for (int j = 0; j < 4; j++) acc[i][j] = (f32x4){0.f, 0.f, 0.f, 0.f};

    gemm_core128(oh, ol, wh, m0, n0, Ah, Al, Bh, acc);

    const int tid = threadIdx.x;
    const int w = tid >> 6, ln = tid & 63;
    const int wm = (w & 1) * 64, wn = (w >> 1) * 64;
    const int lc = ln & 15, quad = ln >> 4;

    #pragma unroll
    for (int nt = 0; nt < 4; nt++) {
        int col = n0 + wn + nt * 16 + lc;
        float bv_ = bias[col];
        #pragma unroll
        for (int mt = 0; mt < 4; mt++) {
            #pragma unroll
            for (int r = 0; r < 4; r++) {
                int m = m0 + wm + mt * 16 + quad * 4 + r;
                Y[(size_t)m * D + col] = acc[mt][nt][r] + bv_;
            }
        }
    }
}

// ---------------- MFMA block-diagonal flash attention (fp16 2-term) ----------------
__global__ __launch_bounds__(256) void attn3_k(
    const f16* __restrict__ Qh, const f16* __restrict__ Ql,
    const f16* __restrict__ Kh, const f16* __restrict__ Vth,
    const int* __restrict__ dstart, const int* __restrict__ dend,
    f16* __restrict__ Ohi, f16* __restrict__ Olo)
{
    const int qt = blockIdx.x, h = blockIdx.y, b = blockIdx.z;
    const int q0 = qt * TQ;
    const size_t bh  = ((size_t)b * H + h) * S;
    const size_t bhv = ((size_t)b * H + h) * HD;

    const int tid = threadIdx.x;
    const int w = tid >> 6, ln = tid & 63;
    const int lc = ln & 15, quad = ln >> 4;

    __shared__ f16 VtHs[64 * 64];
    __shared__ float Ps[4][16 * 64];
    __shared__ int sb[TQ], se[TQ];

    if (tid < TQ) { sb[tid] = dstart[q0 + tid]; se[tid] = dend[q0 + tid]; }

    const size_t qrow = bh + q0 + w * 16 + lc;
    f16x8 qfh[2], qfl[2];
    #pragma unroll
    for (int ks = 0; ks < 2; ks++) {
        qfh[ks] = *(const f16x8*)(Qh + qrow * HD + ks * 32 + quad * 8);
        qfl[ks] = *(const f16x8*)(Ql + qrow * HD + ks * 32 + quad * 8);
    }
    __syncthreads();

    int row_st[4], row_en[4];
    #pragma unroll
    for (int r = 0; r < 4; r++) {
        row_st[r] = sb[w * 16 + quad * 4 + r];
        row_en[r] = se[w * 16 + quad * 4 + r];
    }
    const int kstart = sb[0] & ~63;
    const int kend   = se[TQ - 1];

    f32x4 o[4];
    #pragma unroll
    for (int nt = 0; nt < 4; nt++) o[nt] = (f32x4){0.f, 0.f, 0.f, 0.f};
    f32x4 m_i = (f32x4){NEGBIG, NEGBIG, NEGBIG, NEGBIG};
    f32x4 l_i = (f32x4){0.f, 0.f, 0.f, 0.f};

    for (int j0 = kstart; j0 < kend; j0 += 64) {
        __syncthreads();
        #pragma unroll
        for (int p = 0; p < 2; p++) {
            int idx = tid + p * 256;
            int dim = idx >> 3, g = idx & 7;
            int slot = g ^ (dim & 7);
            *(uint4*)&VtHs[dim * 64 + slot * 8] =
                *(const uint4*)(Vth + (bhv + dim) * S + j0 + g * 8);
        }

        f16x8 kfh[4][2];
        #pragma unroll
        for (int t = 0; t < 4; t++) {
            size_t krow = (bh + j0 + t * 16 + lc) * HD;
            #pragma unroll
            for (int ks = 0; ks < 2; ks++)
                kfh[t][ks] = *(const f16x8*)(Kh + krow + ks * 32 + quad * 8);
        }
        __syncthreads();

        f32x4 sc[4];
        #pragma unroll
        for (int t = 0; t < 4; t++) {
            f32x4 a = (f32x4){0.f, 0.f, 0.f, 0.f};
            #pragma unroll
            for (int ks = 0; ks < 2; ks++) {
                a = __builtin_amdgcn_mfma_f32_16x16x32_f16(qfl[ks], kfh[t][ks], a, 0, 0, 0);
                a = __builtin_amdgcn_mfma_f32_16x16x32_f16(qfh[ks], kfh[t][ks], a, 0, 0, 0);
            }
            int key = j0 + t * 16 + lc;
            #pragma unroll
            for (int r = 0; r < 4; r++) {
                bool valid = (key >= row_st[r]) && (key < row_en[r]);
                sc[t][r] = valid ? a[r] : NEGBIG;
            }
        }

        f32x4 mx = sc[0];
        #pragma unroll
        for (int t = 1; t < 4; t++)
            #pragma unroll
            for (int r = 0; r < 4; r++) mx[r] = fmaxf(mx[r], sc[t][r]);
        #pragma unroll
        for (int off = 1; off <= 8; off <<= 1)
            #pragma unroll
            for (int r = 0; r < 4; r++) mx[r] = fmaxf(mx[r], __shfl_xor(mx[r], off, 64));

        f32x4 m_new, alpha;
        #pragma unroll
        for (int r = 0; r < 4; r++) {
            m_new[r] = fmaxf(m_i[r], mx[r]);
            alpha[r] = __expf(m_i[r] - m_new[r]);
        }

        f32x4 psum = (f32x4){0.f, 0.f, 0.f, 0.f};
        f32x4 pv[4];
        #pragma unroll
        for (int t = 0; t < 4; t++) {
            #pragma unroll
            for (int r = 0; r < 4; r++) {
                float p = __expf(sc[t][r] - m_new[r]);
                p = (sc[t][r] < -5e29f) ? 0.f : p;
                pv[t][r] = p;
                psum[r] += p;
            }
        }
        #pragma unroll
        for (int off = 1; off <= 8; off <<= 1)
            #pragma unroll
            for (int r = 0; r < 4; r++) psum[r] += __shfl_xor(psum[r], off, 64);

        #pragma unroll
        for (int r = 0; r < 4; r++) {
            l_i[r] = l_i[r] * alpha[r] + psum[r];
            m_i[r] = m_new[r];
        }
        #pragma unroll
        for (int nt = 0; nt < 4; nt++)
            #pragma unroll
            for (int r = 0; r < 4; r++) o[nt][r] *= alpha[r];

        #pragma unroll
        for (int t = 0; t < 4; t++) {
            int g = 2 * t + (lc >> 3);
            #pragma unroll
            for (int r = 0; r < 4; r++) {
                int q = quad * 4 + r;
                Ps[w][q * 64 + ((g ^ (q & 7)) * 8) + (lc & 7)] = pv[t][r];
            }
        }
        __syncthreads();

        #pragma unroll
        for (int ks = 0; ks < 2; ks++) {
            int gp = ks * 4 + quad;
            const float* prow = &Ps[w][lc * 64 + ((gp ^ (lc & 7)) * 8)];
            f16x8 ph, pl;
            #pragma unroll
            for (int j = 0; j < 8; j++) {
                float f = prow[j];
                f16 hh = (f16)f;
                ph[j] = hh;
                pl[j] = (f16)(f - (float)hh);
            }
            #pragma unroll
            for (int nt = 0; nt < 4; nt++) {
                int dim = nt * 16 + lc;
                int slot = gp ^ (dim & 7);
                f16x8 vh = *(const f16x8*)&VtHs[dim * 64 + slot * 8];
                o[nt] = __builtin_amdgcn_mfma_f32_16x16x32_f16(pl, vh, o[nt], 0, 0, 0);
                o[nt] = __builtin_amdgcn_mfma_f32_16x16x32_f16(ph, vh, o[nt], 0, 0, 0);
            }
        }
    }

    f32x4 inv;
    #pragma unroll
    for (int r = 0; r < 4; r++) inv[r] = 1.f / l_i[r];
    #pragma unroll
    for (int nt = 0; nt < 4; nt++) {
        int dim = nt * 16 + lc;
        #pragma unroll
        for (int r = 0; r < 4; r++) {
            int q = q0 + w * 16 + quad * 4 + r;
            float val = o[nt][r] * inv[r];
            size_t idx = ((size_t)(b * S + q)) * D + h * 64 + dim;
            f16 hh = (f16)val;
            Ohi[idx] = hh;
            Olo[idx] = (f16)(val - (float)hh);
        }
    }
}

extern "C" void kernel_launch(void* const* d_in, const int* in_sizes, int n_in,
                              void* d_out, int out_size, void* d_ws, size_t ws_size,
                              hipStream_t stream) {
    const float* hs = (const float*)d_in[0];
    const float* wq = (const float*)d_in[1];
    const float* bq = (const float*)d_in[2];
    const float* wk = (const float*)d_in[3];
    const float* bk = (const float*)d_in[4];
    const float* wv = (const float*)d_in[5];
    const float* bv = (const float*)d_in[6];
    const float* wo = (const float*)d_in[7];
    const float* bo = (const float*)d_in[8];
    const int*  doc = (const int*)d_in[9];
    float* out = (float*)d_out;

    const size_t NE = (size_t)B * S * D;       // 4,194,304
    const size_t NW = (size_t)D * D;           // 1,048,576
    f16* xh   = (f16*)d_ws;  f16* xl = xh + NE;   // reused as Ohi/Olo after qkv
    f16* Qhb  = xl + NE;     f16* Qlb = Qhb + NE;
    f16* Khb  = Qlb + NE;    f16* Vth = Khb + NE;
    f16* wqkv = Vth + NE;                        // 3*NW
    f16* woh  = wqkv + 3 * NW;
    int* dstart = (int*)(woh + NW);
    int* dend = dstart + S;

    docbounds_k<<<(S + 255) / 256, 256, 0, stream>>>(doc, dstart, dend);
    split2_k<<<(int)(NE / 8 / 256), 256, 0, stream>>>((const float4*)hs, (f16x8*)xh, (f16x8*)xl, (int)(NE / 8));
    convw_k<<<(int)(4 * NW / 8 / 256), 256, 0, stream>>>(
        (const float4*)wq, (const float4*)wk, (const float4*)wv, (const float4*)wo,
        (f16x8*)wqkv, (f16x8*)woh, (int)(NW / 8));

    qkv_mfma_k<<<dim3(3 * D / 256, (B * S) / 128), 256, 0, stream>>>(
        xh, xl, wqkv, bq, bk, bv, Qhb, Qlb, Khb, Vth);
    attn3_k<<<dim3(S / TQ, H, B), 256, 0, stream>>>(
        Qhb, Qlb, Khb, Vth, dstart, dend, xh, xl);
    out_mfma_k<<<dim3(D / 128, (B * S) / 128), 256, 0, stream>>>(xh, xl, woh, bo, out);
}

// Round 7
// 213.229 us; speedup vs baseline: 1.3551x; 1.3551x over previous
//
#include <hip/hip_runtime.h>
#include <hip/hip_bf16.h>
#include <math.h>

#define B 2
#define S 2048
#define D 1024
#define H 16
#define HD 64
#define SCALE 0.125f
#define NEGBIG -1e30f
#define TQ 64

typedef _Float16 f16;
typedef _Float16 f16x8 __attribute__((ext_vector_type(8)));
typedef _Float16 f16x4 __attribute__((ext_vector_type(4)));
typedef float f32x4  __attribute__((ext_vector_type(4)));

__device__ __forceinline__ void gl_lds16(const void* g, void* l) {
    __builtin_amdgcn_global_load_lds(
        (const __attribute__((address_space(1))) unsigned int*)g,
        (__attribute__((address_space(3))) unsigned int*)l, 16, 0, 0);
}

// ---------------- fp32 -> fp16 convert: X ----------------
__global__ __launch_bounds__(256) void convx_k(const float4* __restrict__ src,
                                               f16x8* __restrict__ dst, int n8) {
    int i = blockIdx.x * blockDim.x + threadIdx.x;
    if (i >= n8) return;
    float4 a = src[2 * i], b = src[2 * i + 1];
    f16x8 h;
    h[0] = (f16)a.x; h[1] = (f16)a.y; h[2] = (f16)a.z; h[3] = (f16)a.w;
    h[4] = (f16)b.x; h[5] = (f16)b.y; h[6] = (f16)b.z; h[7] = (f16)b.w;
    dst[i] = h;
}

// ---------------- all 4 weight matrices -> fp16 in one launch ----------------
__global__ __launch_bounds__(256) void convw_k(
    const float4* __restrict__ wq, const float4* __restrict__ wk,
    const float4* __restrict__ wv, const float4* __restrict__ wo,
    f16x8* __restrict__ wqkv, f16x8* __restrict__ woh, int n8) {
    int i = blockIdx.x * blockDim.x + threadIdx.x;
    if (i >= 4 * n8) return;
    int id = i / n8;
    int j = i - id * n8;
    const float4* src = (id == 0) ? wq : (id == 1) ? wk : (id == 2) ? wv : wo;
    f16x8* dst = (id < 3) ? (wqkv + (size_t)id * n8 + j) : (woh + j);
    float4 a = src[2 * j], b = src[2 * j + 1];
    f16x8 h;
    h[0] = (f16)a.x; h[1] = (f16)a.y; h[2] = (f16)a.z; h[3] = (f16)a.w;
    h[4] = (f16)b.x; h[5] = (f16)b.y; h[6] = (f16)b.z; h[7] = (f16)b.w;
    *dst = h;
}

// ---------------- document span bounds (ids are sorted) ----------------
__global__ void docbounds_k(const int* __restrict__ doc, int* __restrict__ dstart,
                            int* __restrict__ dend) {
    int i = blockIdx.x * blockDim.x + threadIdx.x;
    if (i >= S) return;
    int v = doc[i];
    int lo = 0, hi = S;
    while (lo < hi) { int mid = (lo + hi) >> 1; if (doc[mid] < v) lo = mid + 1; else hi = mid; }
    dstart[i] = lo;
    lo = 0; hi = S;
    while (lo < hi) { int mid = (lo + hi) >> 1; if (doc[mid] <= v) lo = mid + 1; else hi = mid; }
    dend[i] = lo;
}

// ================= fused QKV projection: fp16 1-term, 128x128, z=which =======
// Q: (b,h,s,hd) pre-scaled by SCALE. K: (b,h,s,hd). V: (b,h,hd,s) via LDS
// transpose (two 64-col passes -> only 17.4 KB LDS).
__global__ __launch_bounds__(256) void qkv_mfma_k(
    const f16* __restrict__ xh, const f16* __restrict__ wqkv,
    const float* __restrict__ bq, const float* __restrict__ bk,
    const float* __restrict__ bv,
    f16* __restrict__ Qh, f16* __restrict__ Kh, f16* __restrict__ Vth)
{
    __shared__ union {
        struct { f16 Ah[128 * 32]; f16 Bh[128 * 32]; } s;   // 16 KB
        f16 tr[64 * 136];                                   // 17.4 KB (V pass)
    } lds;

    const int which = blockIdx.z;
    const f16* Bhg = wqkv + (size_t)which * D * D;

    const int tid = threadIdx.x;
    const int w = tid >> 6, ln = tid & 63;
    const int wm = (w & 1) * 64, wn = (w >> 1) * 64;
    const int lc = ln & 15, quad = ln >> 4;
    const int srow = ln >> 2, slot = ln & 3;
    const int m0 = blockIdx.y * 128, n0 = blockIdx.x * 128;

    int a_off[4], b_off[4];
    #pragma unroll
    for (int t = 0; t < 4; t++) {
        int am = wm + t * 16 + lc;
        a_off[t] = am * 32 + ((quad ^ ((am >> 1) & 3)) * 8);
        int bn = wn + t * 16 + lc;
        b_off[t] = bn * 32 + ((quad ^ ((bn >> 1) & 3)) * 8);
    }

    f32x4 acc[4][4];
    #pragma unroll
    for (int i = 0; i < 4; i++)
        #pragma unroll
        for (int j = 0; j < 4; j++) acc[i][j] = (f32x4){0.f, 0.f, 0.f, 0.f};

    for (int k0 = 0; k0 < 1024; k0 += 32) {
        #pragma unroll
        for (int half = 0; half < 2; half++) {
            int rl = half * 64 + w * 16 + srow;
            int q = slot ^ ((rl >> 1) & 3);
            size_t ga = (size_t)(m0 + rl) * 1024 + k0 + q * 8;
            size_t gb = (size_t)(n0 + rl) * 1024 + k0 + q * 8;
            int lofs = (half * 64 + w * 16) * 32;
            gl_lds16(xh + ga, lds.s.Ah + lofs);
            gl_lds16(Bhg + gb, lds.s.Bh + lofs);
        }
        __syncthreads();

        f16x8 ah[4], bh[4];
        #pragma unroll
        for (int t = 0; t < 4; t++) {
            ah[t] = *(const f16x8*)&lds.s.Ah[a_off[t]];
            bh[t] = *(const f16x8*)&lds.s.Bh[b_off[t]];
        }
        #pragma unroll
        for (int mt = 0; mt < 4; mt++)
            #pragma unroll
            for (int nt = 0; nt < 4; nt++)
                acc[mt][nt] = __builtin_amdgcn_mfma_f32_16x16x32_f16(ah[mt], bh[nt], acc[mt][nt], 0, 0, 0);
        __syncthreads();
    }

    if (which < 2) {
        const float* bias = (which == 0) ? bq : bk;
        #pragma unroll
        for (int nt = 0; nt < 4; nt++) {
            int col = n0 + wn + nt * 16 + lc;
            float bv_ = bias[col];
            int h = col >> 6, hd = col & 63;
            #pragma unroll
            for (int mt = 0; mt < 4; mt++) {
                #pragma unroll
                for (int r = 0; r < 4; r++) {
                    int m = m0 + wm + mt * 16 + quad * 4 + r;
                    int bbm = m >> 11, s = m & (S - 1);
                    float val = acc[mt][nt][r] + bv_;
                    if (which == 0) val *= SCALE;
                    size_t idx = (((size_t)(bbm * H + h) * S) + s) * HD + hd;
                    ((which == 0) ? Qh : Kh)[idx] = (f16)val;
                }
            }
        }
    } else {
        // V: two 64-col transpose passes through LDS, coalesced f16x8 stores
        const int bb = m0 >> 11;
        const int sbase = m0 & (S - 1);
        #pragma unroll
        for (int pass = 0; pass < 2; pass++) {
            if ((w >> 1) == pass) {          // waves whose wn matches this pass
                #pragma unroll
                for (int nt = 0; nt < 4; nt++) {
                    int colp = nt * 16 + lc;             // 0..63 within pass
                    float bv_ = bv[n0 + pass * 64 + colp];
                    #pragma unroll
                    for (int mt = 0; mt < 4; mt++) {
                        f16x4 v;
                        #pragma unroll
                        for (int r = 0; r < 4; r++) v[r] = (f16)(acc[mt][nt][r] + bv_);
                        *(f16x4*)&lds.tr[colp * 136 + wm + mt * 16 + quad * 4] = v;
                    }
                }
            }
            __syncthreads();
            #pragma unroll
            for (int p2 = 0; p2 < 4; p2++) {
                int chunk = tid + p2 * 256;     // 0..1023
                int colp = chunk >> 4;          // 0..63
                int oct = chunk & 15;
                f16x8 v = *(const f16x8*)&lds.tr[colp * 136 + oct * 8];
                int vcol = n0 + pass * 64 + colp;
                int h = vcol >> 6, hd = vcol & 63;
                size_t idx = (((size_t)(bb * H + h) * HD) + hd) * S + sbase + oct * 8;
                *(f16x8*)(Vth + idx) = v;
            }
            __syncthreads();
        }
    }
}

// ---------------- output projection (fp16 1-term, 128x128) ----------------
__global__ __launch_bounds__(256) void out_mfma_k(
    const f16* __restrict__ oh, const f16* __restrict__ wh,
    const float* __restrict__ bias, float* __restrict__ Y)
{
    __shared__ f16 Ah[128 * 32], Bh[128 * 32];
    const int tid = threadIdx.x;
    const int w = tid >> 6, ln = tid & 63;
    const int wm = (w & 1) * 64, wn = (w >> 1) * 64;
    const int lc = ln & 15, quad = ln >> 4;
    const int srow = ln >> 2, slot = ln & 3;
    const int m0 = blockIdx.y * 128, n0 = blockIdx.x * 128;

    int a_off[4], b_off[4];
    #pragma unroll
    for (int t = 0; t < 4; t++) {
        int am = wm + t * 16 + lc;
        a_off[t] = am * 32 + ((quad ^ ((am >> 1) & 3)) * 8);
        int bn = wn + t * 16 + lc;
        b_off[t] = bn * 32 + ((quad ^ ((bn >> 1) & 3)) * 8);
    }

    f32x4 acc[4][4];
    #pragma unroll
    for (int i = 0; i < 4; i++)
        #pragma unroll
        for (int j = 0; j < 4; j++) acc[i][j] = (f32x4){0.f, 0.f, 0.f, 0.f};

    for (int k0 = 0; k0 < 1024; k0 += 32) {
        #pragma unroll
        for (int half = 0; half < 2; half++) {
            int rl = half * 64 + w * 16 + srow;
            int q = slot ^ ((rl >> 1) & 3);
            size_t ga = (size_t)(m0 + rl) * 1024 + k0 + q * 8;
            size_t gb = (size_t)(n0 + rl) * 1024 + k0 + q * 8;
            int lofs = (half * 64 + w * 16) * 32;
            gl_lds16(oh + ga, Ah + lofs);
            gl_lds16(wh + gb, Bh + lofs);
        }
        __syncthreads();

        f16x8 ah[4], bh[4];
        #pragma unroll
        for (int t = 0; t < 4; t++) {
            ah[t] = *(const f16x8*)&Ah[a_off[t]];
            bh[t] = *(const f16x8*)&Bh[b_off[t]];
        }
        #pragma unroll
        for (int mt = 0; mt < 4; mt++)
            #pragma unroll
            for (int nt = 0; nt < 4; nt++)
                acc[mt][nt] = __builtin_amdgcn_mfma_f32_16x16x32_f16(ah[mt], bh[nt], acc[mt][nt], 0, 0, 0);
        __syncthreads();
    }

    #pragma unroll
    for (int nt = 0; nt < 4; nt++) {
        int col = n0 + wn + nt * 16 + lc;
        float bv_ = bias[col];
        #pragma unroll
        for (int mt = 0; mt < 4; mt++) {
            #pragma unroll
            for (int r = 0; r < 4; r++) {
                int m = m0 + wm + mt * 16 + quad * 4 + r;
                Y[(size_t)m * D + col] = acc[mt][nt][r] + bv_;
            }
        }
    }
}

// ---------------- MFMA block-diagonal flash attention (pure fp16) ----------------
__global__ __launch_bounds__(256) void attn3_k(
    const f16* __restrict__ Qh, const f16* __restrict__ Kh,
    const f16* __restrict__ Vth,
    const int* __restrict__ dstart, const int* __restrict__ dend,
    f16* __restrict__ Ohi)
{
    const int qt = blockIdx.x, h = blockIdx.y, b = blockIdx.z;
    const int q0 = qt * TQ;
    const size_t bh  = ((size_t)b * H + h) * S;
    const size_t bhv = ((size_t)b * H + h) * HD;

    const int tid = threadIdx.x;
    const int w = tid >> 6, ln = tid & 63;
    const int lc = ln & 15, quad = ln >> 4;

    __shared__ f16 VtHs[64 * 64];
    __shared__ float Ps[4][16 * 64];
    __shared__ int sb[TQ], se[TQ];

    if (tid < TQ) { sb[tid] = dstart[q0 + tid]; se[tid] = dend[q0 + tid]; }

    const size_t qrow = bh + q0 + w * 16 + lc;
    f16x8 qfh[2];
    #pragma unroll
    for (int ks = 0; ks < 2; ks++)
        qfh[ks] = *(const f16x8*)(Qh + qrow * HD + ks * 32 + quad * 8);
    __syncthreads();

    int row_st[4], row_en[4];
    #pragma unroll
    for (int r = 0; r < 4; r++) {
        row_st[r] = sb[w * 16 + quad * 4 + r];
        row_en[r] = se[w * 16 + quad * 4 + r];
    }
    const int kstart = sb[0] & ~63;
    const int kend   = se[TQ - 1];

    f32x4 o[4];
    #pragma unroll
    for (int nt = 0; nt < 4; nt++) o[nt] = (f32x4){0.f, 0.f, 0.f, 0.f};
    f32x4 m_i = (f32x4){NEGBIG, NEGBIG, NEGBIG, NEGBIG};
    f32x4 l_i = (f32x4){0.f, 0.f, 0.f, 0.f};

    for (int j0 = kstart; j0 < kend; j0 += 64) {
        __syncthreads();
        #pragma unroll
        for (int p = 0; p < 2; p++) {
            int idx = tid + p * 256;
            int dim = idx >> 3, g = idx & 7;
            int slot = g ^ (dim & 7);
            *(uint4*)&VtHs[dim * 64 + slot * 8] =
                *(const uint4*)(Vth + (bhv + dim) * S + j0 + g * 8);
        }

        f16x8 kfh[4][2];
        #pragma unroll
        for (int t = 0; t < 4; t++) {
            size_t krow = (bh + j0 + t * 16 + lc) * HD;
            #pragma unroll
            for (int ks = 0; ks < 2; ks++)
                kfh[t][ks] = *(const f16x8*)(Kh + krow + ks * 32 + quad * 8);
        }
        __syncthreads();

        f32x4 sc[4];
        #pragma unroll
        for (int t = 0; t < 4; t++) {
            f32x4 a = (f32x4){0.f, 0.f, 0.f, 0.f};
            #pragma unroll
            for (int ks = 0; ks < 2; ks++)
                a = __builtin_amdgcn_mfma_f32_16x16x32_f16(qfh[ks], kfh[t][ks], a, 0, 0, 0);
            int key = j0 + t * 16 + lc;
            #pragma unroll
            for (int r = 0; r < 4; r++) {
                bool valid = (key >= row_st[r]) && (key < row_en[r]);
                sc[t][r] = valid ? a[r] : NEGBIG;
            }
        }

        f32x4 mx = sc[0];
        #pragma unroll
        for (int t = 1; t < 4; t++)
            #pragma unroll
            for (int r = 0; r < 4; r++) mx[r] = fmaxf(mx[r], sc[t][r]);
        #pragma unroll
        for (int off = 1; off <= 8; off <<= 1)
            #pragma unroll
            for (int r = 0; r < 4; r++) mx[r] = fmaxf(mx[r], __shfl_xor(mx[r], off, 64));

        f32x4 m_new, alpha;
        #pragma unroll
        for (int r = 0; r < 4; r++) {
            m_new[r] = fmaxf(m_i[r], mx[r]);
            alpha[r] = __expf(m_i[r] - m_new[r]);
        }

        f32x4 psum = (f32x4){0.f, 0.f, 0.f, 0.f};
        f32x4 pv[4];
        #pragma unroll
        for (int t = 0; t < 4; t++) {
            #pragma unroll
            for (int r = 0; r < 4; r++) {
                float p = __expf(sc[t][r] - m_new[r]);
                p = (sc[t][r] < -5e29f) ? 0.f : p;
                pv[t][r] = p;
                psum[r] += p;
            }
        }
        #pragma unroll
        for (int off = 1; off <= 8; off <<= 1)
            #pragma unroll
            for (int r = 0; r < 4; r++) psum[r] += __shfl_xor(psum[r], off, 64);

        #pragma unroll
        for (int r = 0; r < 4; r++) {
            l_i[r] = l_i[r] * alpha[r] + psum[r];
            m_i[r] = m_new[r];
        }
        #pragma unroll
        for (int nt = 0; nt < 4; nt++)
            #pragma unroll
            for (int r = 0; r < 4; r++) o[nt][r] *= alpha[r];

        #pragma unroll
        for (int t = 0; t < 4; t++) {
            int g = 2 * t + (lc >> 3);
            #pragma unroll
            for (int r = 0; r < 4; r++) {
                int q = quad * 4 + r;
                Ps[w][q * 64 + ((g ^ (q & 7)) * 8) + (lc & 7)] = pv[t][r];
            }
        }
        __syncthreads();

        #pragma unroll
        for (int ks = 0; ks < 2; ks++) {
            int gp = ks * 4 + quad;
            const float* prow = &Ps[w][lc * 64 + ((gp ^ (lc & 7)) * 8)];
            f16x8 ph;
            #pragma unroll
            for (int j = 0; j < 8; j++) ph[j] = (f16)prow[j];
            #pragma unroll
            for (int nt = 0; nt < 4; nt++) {
                int dim = nt * 16 + lc;
                int slot = gp ^ (dim & 7);
                f16x8 vh = *(const f16x8*)&VtHs[dim * 64 + slot * 8];
                o[nt] = __builtin_amdgcn_mfma_f32_16x16x32_f16(ph, vh, o[nt], 0, 0, 0);
            }
        }
    }

    f32x4 inv;
    #pragma unroll
    for (int r = 0; r < 4; r++) inv[r] = 1.f / l_i[r];
    #pragma unroll
    for (int nt = 0; nt < 4; nt++) {
        int dim = nt * 16 + lc;
        #pragma unroll
        for (int r = 0; r < 4; r++) {
            int q = q0 + w * 16 + quad * 4 + r;
            float val = o[nt][r] * inv[r];
            size_t idx = ((size_t)(b * S + q)) * D + h * 64 + dim;
            Ohi[idx] = (f16)val;
        }
    }
}

extern "C" void kernel_launch(void* const* d_in, const int* in_sizes, int n_in,
                              void* d_out, int out_size, void* d_ws, size_t ws_size,
                              hipStream_t stream) {
    const float* hs = (const float*)d_in[0];
    const float* wq = (const float*)d_in[1];
    const float* bq = (const float*)d_in[2];
    const float* wk = (const float*)d_in[3];
    const float* bk = (const float*)d_in[4];
    const float* wv = (const float*)d_in[5];
    const float* bv = (const float*)d_in[6];
    const float* wo = (const float*)d_in[7];
    const float* bo = (const float*)d_in[8];
    const int*  doc = (const int*)d_in[9];
    float* out = (float*)d_out;

    const size_t NE = (size_t)B * S * D;       // 4,194,304
    const size_t NW = (size_t)D * D;           // 1,048,576
    f16* xh   = (f16*)d_ws;                     // reused as Oh after qkv
    f16* Qhb  = xh + NE;
    f16* Khb  = Qhb + NE;
    f16* Vth  = Khb + NE;
    f16* wqkv = Vth + NE;                       // 3*NW
    f16* woh  = wqkv + 3 * NW;
    int* dstart = (int*)(woh + NW);
    int* dend = dstart + S;

    docbounds_k<<<(S + 255) / 256, 256, 0, stream>>>(doc, dstart, dend);
    convx_k<<<(int)(NE / 8 / 256), 256, 0, stream>>>((const float4*)hs, (f16x8*)xh, (int)(NE / 8));
    convw_k<<<(int)(4 * NW / 8 / 256), 256, 0, stream>>>(
        (const float4*)wq, (const float4*)wk, (const float4*)wv, (const float4*)wo,
        (f16x8*)wqkv, (f16x8*)woh, (int)(NW / 8));

    qkv_mfma_k<<<dim3(D / 128, (B * S) / 128, 3), 256, 0, stream>>>(
        xh, wqkv, bq, bk, bv, Qhb, Khb, Vth);
    attn3_k<<<dim3(S / TQ, H, B), 256, 0, stream>>>(
        Qhb, Khb, Vth, dstart, dend, xh);
    out_mfma_k<<<dim3(D / 128, (B * S) / 128), 256, 0, stream>>>(xh, woh, bo, out);
}

// Round 9
// 201.346 us; speedup vs baseline: 1.4351x; 1.0590x over previous
//
#include <hip/hip_runtime.h>
#include <hip/hip_bf16.h>
#include <math.h>

#define B 2
#define S 2048
#define D 1024
#define H 16
#define HD 64
#define SCALE 0.125f
#define NEGBIG -1e30f

#define NE 4194304   // B*S*D
#define NW 1048576   // D*D
#define NE8 524288
#define NW8 131072

typedef _Float16 f16;
typedef _Float16 f16x8 __attribute__((ext_vector_type(8)));
typedef _Float16 f16x4 __attribute__((ext_vector_type(4)));
typedef float f32x4  __attribute__((ext_vector_type(4)));

__device__ __forceinline__ void gl_lds16(const void* g, void* l) {
    __builtin_amdgcn_global_load_lds(
        (const __attribute__((address_space(1))) unsigned int*)g,
        (__attribute__((address_space(3))) unsigned int*)l, 16, 0, 0);
}

// wave-local LDS fence: compiler ordering + drain this wave's DS queue.
// 0xC07F = vmcnt(63) expcnt(7) lgkmcnt(0) on gfx9-lineage encoding.
__device__ __forceinline__ void wave_lds_fence() {
    __builtin_amdgcn_wave_barrier();
    __builtin_amdgcn_s_waitcnt(0xC07F);
    __builtin_amdgcn_wave_barrier();
}

// ---------- fused prep: X->fp16, 4 weights->fp16 (wq/wk/wv concat), docbounds ----------
__global__ __launch_bounds__(256) void prep_k(
    const float4* __restrict__ hs,
    const float4* __restrict__ wq, const float4* __restrict__ wk,
    const float4* __restrict__ wv, const float4* __restrict__ wo,
    const int* __restrict__ doc,
    f16x8* __restrict__ xh, f16x8* __restrict__ wqkv, f16x8* __restrict__ woh,
    int* __restrict__ dstart, int* __restrict__ dend)
{
    int i = blockIdx.x * blockDim.x + threadIdx.x;
    if (i < NE8 + 4 * NW8) {
        const float4* src;
        f16x8* dst;
        if (i < NE8) { src = hs + 2 * (size_t)i; dst = xh + i; }
        else {
            int j = i - NE8;
            int id = j / NW8, jj = j - id * NW8;
            src = ((id == 0) ? wq : (id == 1) ? wk : (id == 2) ? wv : wo) + 2 * (size_t)jj;
            dst = (id < 3) ? (wqkv + (size_t)id * NW8 + jj) : (woh + jj);
        }
        float4 a = src[0], b = src[1];
        f16x8 h;
        h[0] = (f16)a.x; h[1] = (f16)a.y; h[2] = (f16)a.z; h[3] = (f16)a.w;
        h[4] = (f16)b.x; h[5] = (f16)b.y; h[6] = (f16)b.z; h[7] = (f16)b.w;
        *dst = h;
    } else {
        int s = i - (NE8 + 4 * NW8);
        if (s < S) {
            int v = doc[s];
            int lo = 0, hi = S;
            while (lo < hi) { int mid = (lo + hi) >> 1; if (doc[mid] < v) lo = mid + 1; else hi = mid; }
            dstart[s] = lo;
            lo = 0; hi = S;
            while (lo < hi) { int mid = (lo + hi) >> 1; if (doc[mid] <= v) lo = mid + 1; else hi = mid; }
            dend[s] = lo;
        }
    }
}

// ================= fused QKV projection: fp16, 128x128, z=which =======
__global__ __launch_bounds__(256) void qkv_mfma_k(
    const f16* __restrict__ xh, const f16* __restrict__ wqkv,
    const float* __restrict__ bq, const float* __restrict__ bk,
    const float* __restrict__ bv,
    f16* __restrict__ Qh, f16* __restrict__ Kh, f16* __restrict__ Vth)
{
    __shared__ union {
        struct { f16 Ah[128 * 32]; f16 Bh[128 * 32]; } s;   // 16 KB
        f16 tr[64 * 136];                                   // V transpose pass
    } lds;

    const int which = blockIdx.z;
    const f16* Bhg = wqkv + (size_t)which * D * D;

    const int tid = threadIdx.x;
    const int w = tid >> 6, ln = tid & 63;
    const int wm = (w & 1) * 64, wn = (w >> 1) * 64;
    const int lc = ln & 15, quad = ln >> 4;
    const int srow = ln >> 2, slot = ln & 3;
    const int m0 = blockIdx.y * 128, n0 = blockIdx.x * 128;

    int a_off[4], b_off[4];
    #pragma unroll
    for (int t = 0; t < 4; t++) {
        int am = wm + t * 16 + lc;
        a_off[t] = am * 32 + ((quad ^ ((am >> 1) & 3)) * 8);
        int bn = wn + t * 16 + lc;
        b_off[t] = bn * 32 + ((quad ^ ((bn >> 1) & 3)) * 8);
    }

    f32x4 acc[4][4];
    #pragma unroll
    for (int i = 0; i < 4; i++)
        #pragma unroll
        for (int j = 0; j < 4; j++) acc[i][j] = (f32x4){0.f, 0.f, 0.f, 0.f};

    for (int k0 = 0; k0 < 1024; k0 += 32) {
        #pragma unroll
        for (int half = 0; half < 2; half++) {
            int rl = half * 64 + w * 16 + srow;
            int q = slot ^ ((rl >> 1) & 3);
            size_t ga = (size_t)(m0 + rl) * 1024 + k0 + q * 8;
            size_t gb = (size_t)(n0 + rl) * 1024 + k0 + q * 8;
            int lofs = (half * 64 + w * 16) * 32;
            gl_lds16(xh + ga, lds.s.Ah + lofs);
            gl_lds16(Bhg + gb, lds.s.Bh + lofs);
        }
        __syncthreads();

        f16x8 ah[4], bh[4];
        #pragma unroll
        for (int t = 0; t < 4; t++) {
            ah[t] = *(const f16x8*)&lds.s.Ah[a_off[t]];
            bh[t] = *(const f16x8*)&lds.s.Bh[b_off[t]];
        }
        #pragma unroll
        for (int mt = 0; mt < 4; mt++)
            #pragma unroll
            for (int nt = 0; nt < 4; nt++)
                acc[mt][nt] = __builtin_amdgcn_mfma_f32_16x16x32_f16(ah[mt], bh[nt], acc[mt][nt], 0, 0, 0);
        __syncthreads();
    }

    if (which < 2) {
        const float* bias = (which == 0) ? bq : bk;
        #pragma unroll
        for (int nt = 0; nt < 4; nt++) {
            int col = n0 + wn + nt * 16 + lc;
            float bv_ = bias[col];
            int h = col >> 6, hd = col & 63;
            #pragma unroll
            for (int mt = 0; mt < 4; mt++) {
                #pragma unroll
                for (int r = 0; r < 4; r++) {
                    int m = m0 + wm + mt * 16 + quad * 4 + r;
                    int bbm = m >> 11, s = m & (S - 1);
                    float val = acc[mt][nt][r] + bv_;
                    if (which == 0) val *= SCALE;
                    size_t idx = (((size_t)(bbm * H + h) * S) + s) * HD + hd;
                    ((which == 0) ? Qh : Kh)[idx] = (f16)val;
                }
            }
        }
    } else {
        const int bb = m0 >> 11;
        const int sbase = m0 & (S - 1);
        #pragma unroll
        for (int pass = 0; pass < 2; pass++) {
            if ((w >> 1) == pass) {
                #pragma unroll
                for (int nt = 0; nt < 4; nt++) {
                    int colp = nt * 16 + lc;
                    float bv_ = bv[n0 + pass * 64 + colp];
                    #pragma unroll
                    for (int mt = 0; mt < 4; mt++) {
                        f16x4 v;
                        #pragma unroll
                        for (int r = 0; r < 4; r++) v[r] = (f16)(acc[mt][nt][r] + bv_);
                        *(f16x4*)&lds.tr[colp * 136 + wm + mt * 16 + quad * 4] = v;
                    }
                }
            }
            __syncthreads();
            #pragma unroll
            for (int p2 = 0; p2 < 4; p2++) {
                int chunk = tid + p2 * 256;
                int colp = chunk >> 4;
                int oct = chunk & 15;
                f16x8 v = *(const f16x8*)&lds.tr[colp * 136 + oct * 8];
                int vcol = n0 + pass * 64 + colp;
                int h = vcol >> 6, hd = vcol & 63;
                size_t idx = (((size_t)(bb * H + h) * HD) + hd) * S + sbase + oct * 8;
                *(f16x8*)(Vth + idx) = v;
            }
            __syncthreads();
        }
    }
}

// ---------------- output projection (fp16, 128x128) ----------------
__global__ __launch_bounds__(256) void out_mfma_k(
    const f16* __restrict__ oh, const f16* __restrict__ wh,
    const float* __restrict__ bias, float* __restrict__ Y)
{
    __shared__ f16 Ah[128 * 32], Bh[128 * 32];
    const int tid = threadIdx.x;
    const int w = tid >> 6, ln = tid & 63;
    const int wm = (w & 1) * 64, wn = (w >> 1) * 64;
    const int lc = ln & 15, quad = ln >> 4;
    const int srow = ln >> 2, slot = ln & 3;
    const int m0 = blockIdx.y * 128, n0 = blockIdx.x * 128;

    int a_off[4], b_off[4];
    #pragma unroll
    for (int t = 0; t < 4; t++) {
        int am = wm + t * 16 + lc;
        a_off[t] = am * 32 + ((quad ^ ((am >> 1) & 3)) * 8);
        int bn = wn + t * 16 + lc;
        b_off[t] = bn * 32 + ((quad ^ ((bn >> 1) & 3)) * 8);
    }

    f32x4 acc[4][4];
    #pragma unroll
    for (int i = 0; i < 4; i++)
        #pragma unroll
        for (int j = 0; j < 4; j++) acc[i][j] = (f32x4){0.f, 0.f, 0.f, 0.f};

    for (int k0 = 0; k0 < 1024; k0 += 32) {
        #pragma unroll
        for (int half = 0; half < 2; half++) {
            int rl = half * 64 + w * 16 + srow;
            int q = slot ^ ((rl >> 1) & 3);
            size_t ga = (size_t)(m0 + rl) * 1024 + k0 + q * 8;
            size_t gb = (size_t)(n0 + rl) * 1024 + k0 + q * 8;
            int lofs = (half * 64 + w * 16) * 32;
            gl_lds16(oh + ga, Ah + lofs);
            gl_lds16(wh + gb, Bh + lofs);
        }
        __syncthreads();

        f16x8 ah[4], bh[4];
        #pragma unroll
        for (int t = 0; t < 4; t++) {
            ah[t] = *(const f16x8*)&Ah[a_off[t]];
            bh[t] = *(const f16x8*)&Bh[b_off[t]];
        }
        #pragma unroll
        for (int mt = 0; mt < 4; mt++)
            #pragma unroll
            for (int nt = 0; nt < 4; nt++)
                acc[mt][nt] = __builtin_amdgcn_mfma_f32_16x16x32_f16(ah[mt], bh[nt], acc[mt][nt], 0, 0, 0);
        __syncthreads();
    }

    #pragma unroll
    for (int nt = 0; nt < 4; nt++) {
        int col = n0 + wn + nt * 16 + lc;
        float bv_ = bias[col];
        #pragma unroll
        for (int mt = 0; mt < 4; mt++) {
            #pragma unroll
            for (int r = 0; r < 4; r++) {
                int m = m0 + wm + mt * 16 + quad * 4 + r;
                Y[(size_t)m * D + col] = acc[mt][nt][r] + bv_;
            }
        }
    }
}

// ============ barrier-free per-wave MFMA block-diagonal flash attention ============
// 4 independent waves per block; wave w owns queries qt*64 + w*16 .. +15.
// K and V^T fragments loaded straight from global. P transposed through a
// wave-private ping-pong LDS slab; cross-lane visibility enforced by a
// wave-local lgkmcnt(0) fence (NOT __syncthreads) — fixes the round-8 race.
__global__ __launch_bounds__(256) void attn4_k(
    const f16* __restrict__ Qh, const f16* __restrict__ Kh,
    const f16* __restrict__ Vth,
    const int* __restrict__ dstart, const int* __restrict__ dend,
    f16* __restrict__ Ohi)
{
    const int qt = blockIdx.x, h = blockIdx.y, b = blockIdx.z;
    const int tid = threadIdx.x;
    const int w = tid >> 6, ln = tid & 63;
    const int lc = ln & 15, quad = ln >> 4;
    const int q0 = qt * 64 + w * 16;               // wave's first query
    const size_t bh  = ((size_t)b * H + h) * S;
    const size_t bhv = ((size_t)b * H + h) * HD;

    __shared__ float Ps[4][2][16 * 65];            // wave-private ping-pong

    int row_st[4], row_en[4];
    #pragma unroll
    for (int r = 0; r < 4; r++) {
        row_st[r] = dstart[q0 + quad * 4 + r];
        row_en[r] = dend[q0 + quad * 4 + r];
    }
    const int kstart = dstart[q0] & ~63;           // dstart non-decreasing
    const int kend   = dend[q0 + 15];              // dend non-decreasing

    const size_t qrow = bh + q0 + lc;
    f16x8 qf[2];
    #pragma unroll
    for (int ks = 0; ks < 2; ks++)
        qf[ks] = *(const f16x8*)(Qh + qrow * HD + ks * 32 + quad * 8);

    f32x4 o[4];
    #pragma unroll
    for (int nt = 0; nt < 4; nt++) o[nt] = (f32x4){0.f, 0.f, 0.f, 0.f};
    f32x4 m_i = (f32x4){NEGBIG, NEGBIG, NEGBIG, NEGBIG};
    f32x4 l_i = (f32x4){0.f, 0.f, 0.f, 0.f};

    int it = 0;
    for (int j0 = kstart; j0 < kend; j0 += 64, it ^= 1) {
        float* ps = &Ps[w][it][0];

        // ---- K fragments straight from global (B-layout) ----
        f16x8 kf[4][2];
        #pragma unroll
        for (int t = 0; t < 4; t++) {
            size_t krow = (bh + j0 + t * 16 + lc) * HD;
            #pragma unroll
            for (int ks = 0; ks < 2; ks++)
                kf[t][ks] = *(const f16x8*)(Kh + krow + ks * 32 + quad * 8);
        }

        // ---- scores: S[row=quad*4+r][key=t*16+lc] ----
        f32x4 sc[4];
        #pragma unroll
        for (int t = 0; t < 4; t++) {
            f32x4 a = (f32x4){0.f, 0.f, 0.f, 0.f};
            #pragma unroll
            for (int ks = 0; ks < 2; ks++)
                a = __builtin_amdgcn_mfma_f32_16x16x32_f16(qf[ks], kf[t][ks], a, 0, 0, 0);
            int key = j0 + t * 16 + lc;
            #pragma unroll
            for (int r = 0; r < 4; r++) {
                bool valid = (key >= row_st[r]) && (key < row_en[r]);
                sc[t][r] = valid ? a[r] : NEGBIG;
            }
        }

        // ---- online softmax (16 rows at once, shuffles within 16 lanes) ----
        f32x4 mx = sc[0];
        #pragma unroll
        for (int t = 1; t < 4; t++)
            #pragma unroll
            for (int r = 0; r < 4; r++) mx[r] = fmaxf(mx[r], sc[t][r]);
        #pragma unroll
        for (int off = 1; off <= 8; off <<= 1)
            #pragma unroll
            for (int r = 0; r < 4; r++) mx[r] = fmaxf(mx[r], __shfl_xor(mx[r], off, 64));

        f32x4 m_new, alpha;
        #pragma unroll
        for (int r = 0; r < 4; r++) {
            m_new[r] = fmaxf(m_i[r], mx[r]);
            alpha[r] = __expf(m_i[r] - m_new[r]);
        }

        f32x4 psum = (f32x4){0.f, 0.f, 0.f, 0.f};
        f32x4 pv[4];
        #pragma unroll
        for (int t = 0; t < 4; t++) {
            #pragma unroll
            for (int r = 0; r < 4; r++) {
                float p = __expf(sc[t][r] - m_new[r]);
                p = (sc[t][r] < -5e29f) ? 0.f : p;
                pv[t][r] = p;
                psum[r] += p;
            }
        }
        #pragma unroll
        for (int off = 1; off <= 8; off <<= 1)
            #pragma unroll
            for (int r = 0; r < 4; r++) psum[r] += __shfl_xor(psum[r], off, 64);

        #pragma unroll
        for (int r = 0; r < 4; r++) {
            l_i[r] = l_i[r] * alpha[r] + psum[r];
            m_i[r] = m_new[r];
        }
        #pragma unroll
        for (int nt = 0; nt < 4; nt++)
            #pragma unroll
            for (int r = 0; r < 4; r++) o[nt][r] *= alpha[r];

        // ---- P -> wave-private LDS (C-layout -> A-layout) ----
        #pragma unroll
        for (int t = 0; t < 4; t++) {
            int g = 2 * t + (lc >> 3);
            #pragma unroll
            for (int r = 0; r < 4; r++) {
                int q = quad * 4 + r;
                ps[q * 65 + ((g ^ (q & 7)) * 8) + (lc & 7)] = pv[t][r];
            }
        }

        wave_lds_fence();   // drain this wave's DS writes before cross-lane reads

        // ---- PV: O += P * V, V^T fragments from global ----
        #pragma unroll
        for (int ks = 0; ks < 2; ks++) {
            int gp = ks * 4 + quad;
            const float* prow = &ps[lc * 65 + ((gp ^ (lc & 7)) * 8)];
            f16x8 ph;
            #pragma unroll
            for (int j = 0; j < 8; j++) ph[j] = (f16)prow[j];
            #pragma unroll
            for (int nt = 0; nt < 4; nt++) {
                int dim = nt * 16 + lc;
                f16x8 vh = *(const f16x8*)(Vth + (bhv + dim) * S + j0 + gp * 8);
                o[nt] = __builtin_amdgcn_mfma_f32_16x16x32_f16(ph, vh, o[nt], 0, 0, 0);
            }
        }
    }

    // ---- epilogue: O[(b*S+q)*D + h*64 + dim] as fp16 for out-proj ----
    f32x4 inv;
    #pragma unroll
    for (int r = 0; r < 4; r++) inv[r] = 1.f / l_i[r];
    #pragma unroll
    for (int nt = 0; nt < 4; nt++) {
        int dim = nt * 16 + lc;
        #pragma unroll
        for (int r = 0; r < 4; r++) {
            int q = q0 + quad * 4 + r;
            float val = o[nt][r] * inv[r];
            size_t idx = ((size_t)(b * S + q)) * D + h * 64 + dim;
            Ohi[idx] = (f16)val;
        }
    }
}

extern "C" void kernel_launch(void* const* d_in, const int* in_sizes, int n_in,
                              void* d_out, int out_size, void* d_ws, size_t ws_size,
                              hipStream_t stream) {
    const float* hs = (const float*)d_in[0];
    const float* wq = (const float*)d_in[1];
    const float* bq = (const float*)d_in[2];
    const float* wk = (const float*)d_in[3];
    const float* bk = (const float*)d_in[4];
    const float* wv = (const float*)d_in[5];
    const float* bv = (const float*)d_in[6];
    const float* wo = (const float*)d_in[7];
    const float* bo = (const float*)d_in[8];
    const int*  doc = (const int*)d_in[9];
    float* out = (float*)d_out;

    f16* xh   = (f16*)d_ws;                     // reused as Oh after attention
    f16* Qhb  = xh + NE;
    f16* Khb  = Qhb + NE;
    f16* Vth  = Khb + NE;
    f16* wqkv = Vth + NE;                       // 3*NW
    f16* woh  = wqkv + 3 * (size_t)NW;
    int* dstart = (int*)(woh + NW);
    int* dend = dstart + S;

    prep_k<<<(NE8 + 4 * NW8 + S + 255) / 256, 256, 0, stream>>>(
        (const float4*)hs, (const float4*)wq, (const float4*)wk,
        (const float4*)wv, (const float4*)wo, doc,
        (f16x8*)xh, (f16x8*)wqkv, (f16x8*)woh, dstart, dend);

    qkv_mfma_k<<<dim3(D / 128, (B * S) / 128, 3), 256, 0, stream>>>(
        xh, wqkv, bq, bk, bv, Qhb, Khb, Vth);
    attn4_k<<<dim3(S / 64, H, B), 256, 0, stream>>>(
        Qhb, Khb, Vth, dstart, dend, xh);
    out_mfma_k<<<dim3(D / 128, (B * S) / 128), 256, 0, stream>>>(xh, woh, bo, out);
}

// Round 10
// 192.889 us; speedup vs baseline: 1.4980x; 1.0438x over previous
//
#include <hip/hip_runtime.h>
#include <hip/hip_bf16.h>
#include <math.h>

#define B 2
#define S 2048
#define D 1024
#define H 16
#define HD 64
#define SCALE 0.125f
#define NEGBIG -1e30f

#define NE 4194304   // B*S*D
#define NW 1048576   // D*D
#define NE8 524288
#define NW8 131072

typedef _Float16 f16;
typedef _Float16 f16x8 __attribute__((ext_vector_type(8)));
typedef _Float16 f16x4 __attribute__((ext_vector_type(4)));
typedef float f32x4  __attribute__((ext_vector_type(4)));

__device__ __forceinline__ void gl_lds16(const void* g, void* l) {
    __builtin_amdgcn_global_load_lds(
        (const __attribute__((address_space(1))) unsigned int*)g,
        (__attribute__((address_space(3))) unsigned int*)l, 16, 0, 0);
}

// wave-local LDS fence: compiler ordering + drain this wave's DS queue.
// 0xC07F = vmcnt(63) expcnt(7) lgkmcnt(0).
__device__ __forceinline__ void wave_lds_fence() {
    __builtin_amdgcn_wave_barrier();
    __builtin_amdgcn_s_waitcnt(0xC07F);
    __builtin_amdgcn_wave_barrier();
}

// ---------- fused prep: X->fp16, 4 weights->fp16 (wq/wk/wv concat), docbounds ----------
__global__ __launch_bounds__(256) void prep_k(
    const float4* __restrict__ hs,
    const float4* __restrict__ wq, const float4* __restrict__ wk,
    const float4* __restrict__ wv, const float4* __restrict__ wo,
    const int* __restrict__ doc,
    f16x8* __restrict__ xh, f16x8* __restrict__ wqkv, f16x8* __restrict__ woh,
    int* __restrict__ dstart, int* __restrict__ dend)
{
    int i = blockIdx.x * blockDim.x + threadIdx.x;
    if (i < NE8 + 4 * NW8) {
        const float4* src;
        f16x8* dst;
        if (i < NE8) { src = hs + 2 * (size_t)i; dst = xh + i; }
        else {
            int j = i - NE8;
            int id = j / NW8, jj = j - id * NW8;
            src = ((id == 0) ? wq : (id == 1) ? wk : (id == 2) ? wv : wo) + 2 * (size_t)jj;
            dst = (id < 3) ? (wqkv + (size_t)id * NW8 + jj) : (woh + jj);
        }
        float4 a = src[0], b = src[1];
        f16x8 h;
        h[0] = (f16)a.x; h[1] = (f16)a.y; h[2] = (f16)a.z; h[3] = (f16)a.w;
        h[4] = (f16)b.x; h[5] = (f16)b.y; h[6] = (f16)b.z; h[7] = (f16)b.w;
        *dst = h;
    } else {
        int s = i - (NE8 + 4 * NW8);
        if (s < S) {
            int v = doc[s];
            int lo = 0, hi = S;
            while (lo < hi) { int mid = (lo + hi) >> 1; if (doc[mid] < v) lo = mid + 1; else hi = mid; }
            dstart[s] = lo;
            lo = 0; hi = S;
            while (lo < hi) { int mid = (lo + hi) >> 1; if (doc[mid] <= v) lo = mid + 1; else hi = mid; }
            dend[s] = lo;
        }
    }
}

// ================= fused QKV projection: fp16, 128x128 tile, BK=64 =======
// Octet swizzle: LDS row = 64 f16 = 128 B; slot s holds global octet s^(row&7).
__global__ __launch_bounds__(256) void qkv_mfma_k(
    const f16* __restrict__ xh, const f16* __restrict__ wqkv,
    const float* __restrict__ bq, const float* __restrict__ bk,
    const float* __restrict__ bv,
    f16* __restrict__ Qh, f16* __restrict__ Kh, f16* __restrict__ Vth)
{
    __shared__ union {
        struct { f16 Ah[128 * 64]; f16 Bh[128 * 64]; } s;   // 32 KB
        f16 tr[64 * 136];                                   // V transpose pass
    } lds;

    const int which = blockIdx.z;
    const f16* Bhg = wqkv + (size_t)which * D * D;

    const int tid = threadIdx.x;
    const int w = tid >> 6, ln = tid & 63;
    const int wm = (w & 1) * 64, wn = (w >> 1) * 64;
    const int lc = ln & 15, quad = ln >> 4;
    const int m0 = blockIdx.y * 128, n0 = blockIdx.x * 128;

    f32x4 acc[4][4];
    #pragma unroll
    for (int i = 0; i < 4; i++)
        #pragma unroll
        for (int j = 0; j < 4; j++) acc[i][j] = (f32x4){0.f, 0.f, 0.f, 0.f};

    for (int k0 = 0; k0 < 1024; k0 += 64) {
        #pragma unroll
        for (int i = 0; i < 4; i++) {
            int rl = w * 32 + i * 8 + (ln >> 3);      // row 0..127
            int oc = (ln & 7) ^ (rl & 7);             // global octet for this slot
            size_t ga = (size_t)(m0 + rl) * 1024 + k0 + oc * 8;
            size_t gb = (size_t)(n0 + rl) * 1024 + k0 + oc * 8;
            int lofs = (w * 32 + i * 8) * 64;         // wave-uniform base
            gl_lds16(xh + ga, lds.s.Ah + lofs);
            gl_lds16(Bhg + gb, lds.s.Bh + lofs);
        }
        __syncthreads();

        #pragma unroll
        for (int ks = 0; ks < 2; ks++) {
            f16x8 ah[4], bh[4];
            #pragma unroll
            for (int t = 0; t < 4; t++) {
                int am = wm + t * 16 + lc;
                ah[t] = *(const f16x8*)&lds.s.Ah[am * 64 + (((ks * 4 + quad) ^ (am & 7)) * 8)];
                int bn = wn + t * 16 + lc;
                bh[t] = *(const f16x8*)&lds.s.Bh[bn * 64 + (((ks * 4 + quad) ^ (bn & 7)) * 8)];
            }
            #pragma unroll
            for (int mt = 0; mt < 4; mt++)
                #pragma unroll
                for (int nt = 0; nt < 4; nt++)
                    acc[mt][nt] = __builtin_amdgcn_mfma_f32_16x16x32_f16(ah[mt], bh[nt], acc[mt][nt], 0, 0, 0);
        }
        __syncthreads();
    }

    if (which < 2) {
        const float* bias = (which == 0) ? bq : bk;
        #pragma unroll
        for (int nt = 0; nt < 4; nt++) {
            int col = n0 + wn + nt * 16 + lc;
            float bv_ = bias[col];
            int h = col >> 6, hd = col & 63;
            #pragma unroll
            for (int mt = 0; mt < 4; mt++) {
                #pragma unroll
                for (int r = 0; r < 4; r++) {
                    int m = m0 + wm + mt * 16 + quad * 4 + r;
                    int bbm = m >> 11, s = m & (S - 1);
                    float val = acc[mt][nt][r] + bv_;
                    if (which == 0) val *= SCALE;
                    size_t idx = (((size_t)(bbm * H + h) * S) + s) * HD + hd;
                    ((which == 0) ? Qh : Kh)[idx] = (f16)val;
                }
            }
        }
    } else {
        const int bb = m0 >> 11;
        const int sbase = m0 & (S - 1);
        #pragma unroll
        for (int pass = 0; pass < 2; pass++) {
            if ((w >> 1) == pass) {
                #pragma unroll
                for (int nt = 0; nt < 4; nt++) {
                    int colp = nt * 16 + lc;
                    float bv_ = bv[n0 + pass * 64 + colp];
                    #pragma unroll
                    for (int mt = 0; mt < 4; mt++) {
                        f16x4 v;
                        #pragma unroll
                        for (int r = 0; r < 4; r++) v[r] = (f16)(acc[mt][nt][r] + bv_);
                        *(f16x4*)&lds.tr[colp * 136 + wm + mt * 16 + quad * 4] = v;
                    }
                }
            }
            __syncthreads();
            #pragma unroll
            for (int p2 = 0; p2 < 4; p2++) {
                int chunk = tid + p2 * 256;
                int colp = chunk >> 4;
                int oct = chunk & 15;
                f16x8 v = *(const f16x8*)&lds.tr[colp * 136 + oct * 8];
                int vcol = n0 + pass * 64 + colp;
                int h = vcol >> 6, hd = vcol & 63;
                size_t idx = (((size_t)(bb * H + h) * HD) + hd) * S + sbase + oct * 8;
                *(f16x8*)(Vth + idx) = v;
            }
            __syncthreads();
        }
    }
}

// ---------------- output projection: 128m x 64n tile, BK=64, 512 blocks ----------------
__global__ __launch_bounds__(256) void out_mfma_k(
    const f16* __restrict__ oh, const f16* __restrict__ wh,
    const float* __restrict__ bias, float* __restrict__ Y)
{
    __shared__ f16 Ah[128 * 64], Bh[64 * 64];    // 16 + 8 KB
    const int tid = threadIdx.x;
    const int w = tid >> 6, ln = tid & 63;
    const int wm = (w & 1) * 64, wn = (w >> 1) * 32;
    const int lc = ln & 15, quad = ln >> 4;
    const int m0 = blockIdx.y * 128, n0 = blockIdx.x * 64;

    f32x4 acc[4][2];
    #pragma unroll
    for (int i = 0; i < 4; i++)
        #pragma unroll
        for (int j = 0; j < 2; j++) acc[i][j] = (f32x4){0.f, 0.f, 0.f, 0.f};

    for (int k0 = 0; k0 < 1024; k0 += 64) {
        #pragma unroll
        for (int i = 0; i < 4; i++) {
            int rl = w * 32 + i * 8 + (ln >> 3);
            int oc = (ln & 7) ^ (rl & 7);
            gl_lds16(oh + (size_t)(m0 + rl) * 1024 + k0 + oc * 8, Ah + (w * 32 + i * 8) * 64);
        }
        #pragma unroll
        for (int i = 0; i < 2; i++) {
            int rl = w * 16 + i * 8 + (ln >> 3);
            int oc = (ln & 7) ^ (rl & 7);
            gl_lds16(wh + (size_t)(n0 + rl) * 1024 + k0 + oc * 8, Bh + (w * 16 + i * 8) * 64);
        }
        __syncthreads();

        #pragma unroll
        for (int ks = 0; ks < 2; ks++) {
            f16x8 ah[4], bh[2];
            #pragma unroll
            for (int t = 0; t < 4; t++) {
                int am = wm + t * 16 + lc;
                ah[t] = *(const f16x8*)&Ah[am * 64 + (((ks * 4 + quad) ^ (am & 7)) * 8)];
            }
            #pragma unroll
            for (int t = 0; t < 2; t++) {
                int bn = wn + t * 16 + lc;
                bh[t] = *(const f16x8*)&Bh[bn * 64 + (((ks * 4 + quad) ^ (bn & 7)) * 8)];
            }
            #pragma unroll
            for (int mt = 0; mt < 4; mt++)
                #pragma unroll
                for (int nt = 0; nt < 2; nt++)
                    acc[mt][nt] = __builtin_amdgcn_mfma_f32_16x16x32_f16(ah[mt], bh[nt], acc[mt][nt], 0, 0, 0);
        }
        __syncthreads();
    }

    #pragma unroll
    for (int nt = 0; nt < 2; nt++) {
        int col = n0 + wn + nt * 16 + lc;
        float bv_ = bias[col];
        #pragma unroll
        for (int mt = 0; mt < 4; mt++) {
            #pragma unroll
            for (int r = 0; r < 4; r++) {
                int m = m0 + wm + mt * 16 + quad * 4 + r;
                Y[(size_t)m * D + col] = acc[mt][nt][r] + bv_;
            }
        }
    }
}

// ============ barrier-free per-wave flash attention, K-prefetch pipeline ============
__device__ __forceinline__ void load_kfrag(
    const f16* __restrict__ Kh, size_t bh, int j0, int lc, int quad, f16x8 kf[4][2])
{
    #pragma unroll
    for (int t = 0; t < 4; t++) {
        size_t krow = (bh + j0 + t * 16 + lc) * HD;
        #pragma unroll
        for (int ks = 0; ks < 2; ks++)
            kf[t][ks] = *(const f16x8*)(Kh + krow + ks * 32 + quad * 8);
    }
}

__global__ __launch_bounds__(256) void attn4_k(
    const f16* __restrict__ Qh, const f16* __restrict__ Kh,
    const f16* __restrict__ Vth,
    const int* __restrict__ dstart, const int* __restrict__ dend,
    f16* __restrict__ Ohi)
{
    const int qt = blockIdx.x, h = blockIdx.y, b = blockIdx.z;
    const int tid = threadIdx.x;
    const int w = tid >> 6, ln = tid & 63;
    const int lc = ln & 15, quad = ln >> 4;
    const int q0 = qt * 64 + w * 16;
    const size_t bh  = ((size_t)b * H + h) * S;
    const size_t bhv = ((size_t)b * H + h) * HD;

    __shared__ float Ps[4][2][16 * 65];            // wave-private ping-pong

    int row_st[4], row_en[4];
    #pragma unroll
    for (int r = 0; r < 4; r++) {
        row_st[r] = dstart[q0 + quad * 4 + r];
        row_en[r] = dend[q0 + quad * 4 + r];
    }
    const int kstart = dstart[q0] & ~63;
    const int kend   = dend[q0 + 15];

    const size_t qrow = bh + q0 + lc;
    f16x8 qf[2];
    #pragma unroll
    for (int ks = 0; ks < 2; ks++)
        qf[ks] = *(const f16x8*)(Qh + qrow * HD + ks * 32 + quad * 8);

    f32x4 o[4];
    #pragma unroll
    for (int nt = 0; nt < 4; nt++) o[nt] = (f32x4){0.f, 0.f, 0.f, 0.f};
    f32x4 m_i = (f32x4){NEGBIG, NEGBIG, NEGBIG, NEGBIG};
    f32x4 l_i = (f32x4){0.f, 0.f, 0.f, 0.f};

    f16x8 kf[4][2], kf2[4][2];
    load_kfrag(Kh, bh, kstart, lc, quad, kf);

    int it = 0;
    for (int j0 = kstart; j0 < kend; j0 += 64, it ^= 1) {
        float* ps = &Ps[w][it][0];
        const bool more = (j0 + 64) < kend;
        if (more) load_kfrag(Kh, bh, j0 + 64, lc, quad, kf2);   // in flight across chunk

        // ---- scores: S[row=quad*4+r][key=t*16+lc] ----
        f32x4 sc[4];
        #pragma unroll
        for (int t = 0; t < 4; t++) {
            f32x4 a = (f32x4){0.f, 0.f, 0.f, 0.f};
            #pragma unroll
            for (int ks = 0; ks < 2; ks++)
                a = __builtin_amdgcn_mfma_f32_16x16x32_f16(qf[ks], kf[t][ks], a, 0, 0, 0);
            int key = j0 + t * 16 + lc;
            #pragma unroll
            for (int r = 0; r < 4; r++) {
                bool valid = (key >= row_st[r]) && (key < row_en[r]);
                sc[t][r] = valid ? a[r] : NEGBIG;
            }
        }

        // ---- online softmax ----
        f32x4 mx = sc[0];
        #pragma unroll
        for (int t = 1; t < 4; t++)
            #pragma unroll
            for (int r = 0; r < 4; r++) mx[r] = fmaxf(mx[r], sc[t][r]);
        #pragma unroll
        for (int off = 1; off <= 8; off <<= 1)
            #pragma unroll
            for (int r = 0; r < 4; r++) mx[r] = fmaxf(mx[r], __shfl_xor(mx[r], off, 64));

        f32x4 m_new, alpha;
        #pragma unroll
        for (int r = 0; r < 4; r++) {
            m_new[r] = fmaxf(m_i[r], mx[r]);
            alpha[r] = __expf(m_i[r] - m_new[r]);
        }

        f32x4 psum = (f32x4){0.f, 0.f, 0.f, 0.f};
        f32x4 pv[4];
        #pragma unroll
        for (int t = 0; t < 4; t++) {
            #pragma unroll
            for (int r = 0; r < 4; r++) {
                float p = __expf(sc[t][r] - m_new[r]);
                p = (sc[t][r] < -5e29f) ? 0.f : p;
                pv[t][r] = p;
                psum[r] += p;
            }
        }
        #pragma unroll
        for (int off = 1; off <= 8; off <<= 1)
            #pragma unroll
            for (int r = 0; r < 4; r++) psum[r] += __shfl_xor(psum[r], off, 64);

        #pragma unroll
        for (int r = 0; r < 4; r++) {
            l_i[r] = l_i[r] * alpha[r] + psum[r];
            m_i[r] = m_new[r];
        }
        #pragma unroll
        for (int nt = 0; nt < 4; nt++)
            #pragma unroll
            for (int r = 0; r < 4; r++) o[nt][r] *= alpha[r];

        // ---- V fragment loads issued BEFORE the fence (latency overlap) ----
        f16x8 vh[2][4];
        #pragma unroll
        for (int ks = 0; ks < 2; ks++) {
            int gp = ks * 4 + quad;
            #pragma unroll
            for (int nt = 0; nt < 4; nt++) {
                int dim = nt * 16 + lc;
                vh[ks][nt] = *(const f16x8*)(Vth + (bhv + dim) * S + j0 + gp * 8);
            }
        }

        // ---- P -> wave-private LDS (C-layout -> A-layout) ----
        #pragma unroll
        for (int t = 0; t < 4; t++) {
            int g = 2 * t + (lc >> 3);
            #pragma unroll
            for (int r = 0; r < 4; r++) {
                int q = quad * 4 + r;
                ps[q * 65 + ((g ^ (q & 7)) * 8) + (lc & 7)] = pv[t][r];
            }
        }

        wave_lds_fence();   // drain this wave's DS writes before cross-lane reads

        // ---- PV: O += P * V ----
        #pragma unroll
        for (int ks = 0; ks < 2; ks++) {
            int gp = ks * 4 + quad;
            const float* prow = &ps[lc * 65 + ((gp ^ (lc & 7)) * 8)];
            f16x8 ph;
            #pragma unroll
            for (int j = 0; j < 8; j++) ph[j] = (f16)prow[j];
            #pragma unroll
            for (int nt = 0; nt < 4; nt++)
                o[nt] = __builtin_amdgcn_mfma_f32_16x16x32_f16(ph, vh[ks][nt], o[nt], 0, 0, 0);
        }

        if (more) {
            #pragma unroll
            for (int t = 0; t < 4; t++)
                #pragma unroll
                for (int ks = 0; ks < 2; ks++) kf[t][ks] = kf2[t][ks];
        }
    }

    // ---- epilogue ----
    f32x4 inv;
    #pragma unroll
    for (int r = 0; r < 4; r++) inv[r] = 1.f / l_i[r];
    #pragma unroll
    for (int nt = 0; nt < 4; nt++) {
        int dim = nt * 16 + lc;
        #pragma unroll
        for (int r = 0; r < 4; r++) {
            int q = q0 + quad * 4 + r;
            float val = o[nt][r] * inv[r];
            size_t idx = ((size_t)(b * S + q)) * D + h * 64 + dim;
            Ohi[idx] = (f16)val;
        }
    }
}

extern "C" void kernel_launch(void* const* d_in, const int* in_sizes, int n_in,
                              void* d_out, int out_size, void* d_ws, size_t ws_size,
                              hipStream_t stream) {
    const float* hs = (const float*)d_in[0];
    const float* wq = (const float*)d_in[1];
    const float* bq = (const float*)d_in[2];
    const float* wk = (const float*)d_in[3];
    const float* bk = (const float*)d_in[4];
    const float* wv = (const float*)d_in[5];
    const float* bv = (const float*)d_in[6];
    const float* wo = (const float*)d_in[7];
    const float* bo = (const float*)d_in[8];
    const int*  doc = (const int*)d_in[9];
    float* out = (float*)d_out;

    f16* xh   = (f16*)d_ws;                     // reused as Oh after attention
    f16* Qhb  = xh + NE;
    f16* Khb  = Qhb + NE;
    f16* Vth  = Khb + NE;
    f16* wqkv = Vth + NE;                       // 3*NW
    f16* woh  = wqkv + 3 * (size_t)NW;
    int* dstart = (int*)(woh + NW);
    int* dend = dstart + S;

    prep_k<<<(NE8 + 4 * NW8 + S + 255) / 256, 256, 0, stream>>>(
        (const float4*)hs, (const float4*)wq, (const float4*)wk,
        (const float4*)wv, (const float4*)wo, doc,
        (f16x8*)xh, (f16x8*)wqkv, (f16x8*)woh, dstart, dend);

    qkv_mfma_k<<<dim3(D / 128, (B * S) / 128, 3), 256, 0, stream>>>(
        xh, wqkv, bq, bk, bv, Qhb, Khb, Vth);
    attn4_k<<<dim3(S / 64, H, B), 256, 0, stream>>>(
        Qhb, Khb, Vth, dstart, dend, xh);
    out_mfma_k<<<dim3(D / 64, (B * S) / 128), 256, 0, stream>>>(xh, woh, bo, out);
}